// Round 9
// baseline (22868.135 us; speedup 1.0000x reference)
//
#include <hip/hip_runtime.h>
#include <hip/hip_bf16.h>

// SpatialLSTM: B=64, T=2048, D=128, H=256 (4H=1024)
// R9 = R7 (batch-pair pipelined slots, fused {f32 h,u32 ctr} packets, parity
// double-buffer, lgkm-only barriers) + DUAL-MAILBOX exchange:
//   producer: plain store -> L2 mailbox (same-XCD peers hit shared L2 ~250cy)
//             + agent store -> LLC mailbox (fallback, always correct)
//   consumer: sc0-poll L2 mailbox (48 tries), then agent-poll LLC mailbox.
// Clique {g*32+pair} is XCD-local under round-robin (32 % 8 == 0); if the
// mapping ever changes, the LLC fallback keeps it correct.
#define BB 64
#define TT 2048
#define DD 128
#define HH 256
#define G4 1024
#define TC 16

typedef _Float16 half2_t __attribute__((ext_vector_type(2)));

#if __has_builtin(__builtin_amdgcn_fdot2)
#define FDOT2(a, b, c) __builtin_amdgcn_fdot2((a), (b), (c), false)
#else
__device__ __forceinline__ float FDOT2(half2_t a, half2_t b, float c) {
    return c + (float)a[0] * (float)b[0] + (float)a[1] * (float)b[1];
}
#endif

__device__ __forceinline__ half2_t u2h(unsigned int u) {
    union { unsigned int u; half2_t h; } x; x.u = u; return x.h;
}
__device__ __forceinline__ unsigned int pkf16(float a, float b) {
    union { _Float16 h[2]; unsigned int u; } x;
    x.h[0] = (_Float16)a; x.h[1] = (_Float16)b; return x.u;
}
__device__ __forceinline__ unsigned short f16b(float a) {
    union { _Float16 h; unsigned short u; } x; x.h = (_Float16)a; return x.u;
}
__device__ __forceinline__ float sigf(float x) {
    return 1.0f / (1.0f + __expf(-x));
}
__device__ __forceinline__ float tanh_fast(float x) {
    return 1.0f - 2.0f / (__expf(2.0f * x) + 1.0f);
}
// LDS-ordering-only barrier (no vmcnt store-ack drain; peers poll the caches)
__device__ __forceinline__ void bar_lgkm() {
    asm volatile("s_waitcnt lgkmcnt(0)\n\ts_barrier" ::: "memory");
}
// plain writeback store: lands in this XCD's L2 (allocating) -> same-XCD
// consumers' sc0 loads see it at L2 latency.
__device__ __forceinline__ void store_l2(unsigned long long* p, unsigned long long v) {
    asm volatile("global_store_dwordx2 %0, %1, off" :: "v"(p), "v"(v) : "memory");
}
// sc0 load: bypass L1 (per-CU, non-coherent), read the shared XCD L2.
__device__ __forceinline__ unsigned long long load_l2(const unsigned long long* p) {
    unsigned long long v;
    asm volatile("global_load_dwordx2 %0, %1, off sc0\n\ts_waitcnt vmcnt(0)"
                 : "=v"(v) : "v"(p) : "memory");
    return v;
}

// ---- zero a mailbox region (counters must be < 1 every launch; d_ws keeps
// stale packets from prior graph replays) ----
__global__ void zero_hglob(unsigned long long* hglob) {
    hglob[blockIdx.x * 256 + threadIdx.x] = 0ull;
}

// ---- pack slice-columns: src f32 [K][1024] -> dst f16 [8 slices][128 c][K]
// local col c of slice g <-> global gate col (c>>5)*256 + g*32 + (c&31)
__global__ void __launch_bounds__(128)
pack_slices(const float* __restrict__ src, unsigned short* __restrict__ dst, int K)
{
    const int g = blockIdx.x, kb = blockIdx.y, c = threadIdx.x;
    const int gc = ((c >> 5) << 8) + (g << 5) + (c & 31);
    unsigned int* d32 = (unsigned int*)dst;
    const int dbase = ((g << 7) + c) * K + kb * 64;     // half index, even
    for (int kk = 0; kk < 64; kk += 2) {
        const float a = src[(size_t)(kb * 64 + kk) * G4 + gc];
        const float b = src[(size_t)(kb * 64 + kk + 1) * G4 + gc];
        d32[(dbase + kk) >> 1] = pkf16(a, b);
    }
}

// ============================ R9 main kernel ================================
// grid 256: pair = blk&31 (2 batches), g = blk>>5 (slice of 32 h-cols)
extern "C" __global__ void __launch_bounds__(512, 2)
lstm_pipe2(const float* __restrict__ X, const unsigned short* __restrict__ Upack,
           const unsigned short* __restrict__ Wpack, const float* __restrict__ bias,
           const float* __restrict__ h0, const float* __restrict__ c0,
           unsigned long long* __restrict__ mbx2,   // L2 mailbox
           unsigned long long* __restrict__ mbxa,   // LLC mailbox (fallback)
           float* __restrict__ out)
{
    __shared__ __align__(16) uint4 Ulds4[128 * 32];      // 64 KB, swizzled
    __shared__ __align__(16) uint4 Wlds4[128 * 16];      // 32 KB, swizzled
    __shared__ float xw[2][TC][128];                     // 16 KB
    __shared__ __align__(16) unsigned short Xs[2 * TC * DD]; // 8 KB (f16)
    __shared__ float gvp[4][128];                        // 2 KB partials
    __shared__ __align__(16) unsigned short hsh[2 * HH]; // 1 KB

    const int pair = blockIdx.x & 31;
    const int g = blockIdx.x >> 5;
    const int b0 = pair * 2;
    const int tid = threadIdx.x;
    const int wave = tid >> 6, lane = tid & 63;
    const int c = tid & 127, s = tid >> 7;               // local col, k-quarter

    {
        const uint4* Usrc = (const uint4*)(Upack + (size_t)g * 32768);
        #pragma unroll
        for (int i = 0; i < 8; ++i) {
            const int idx = i * 512 + tid;
            const int cc = idx >> 5, gr = idx & 31;
            Ulds4[cc * 32 + (gr ^ (cc & 31))] = Usrc[idx];
        }
        const uint4* Wsrc = (const uint4*)(Wpack + (size_t)g * 16384);
        #pragma unroll
        for (int i = 0; i < 4; ++i) {
            const int idx = i * 512 + tid;
            const int cc = idx >> 4, gr = idx & 15;
            Wlds4[cc * 16 + (gr ^ (cc & 15))] = Wsrc[idx];
        }
    }
    hsh[tid] = f16b(h0[(size_t)(b0 + (tid >> 8)) * HH + (tid & 255)]);
    float c_reg0 = 0.0f, c_reg1 = 0.0f, h_last0 = 0.0f, h_last1 = 0.0f;
    if (wave == 0 && lane < 32) {
        c_reg0 = c0[(size_t)b0 * HH + (g << 5) + lane];
        c_reg1 = c0[(size_t)(b0 + 1) * HH + (g << 5) + lane];
        h_last0 = h0[(size_t)b0 * HH + (g << 5) + lane];
        h_last1 = h0[(size_t)(b0 + 1) * HH + (g << 5) + lane];
    }
    const float bc = bias[((c >> 5) << 8) + (g << 5) + (c & 31)];
    __syncthreads();

    const size_t obase0 = (size_t)b0 * TT * HH + (g << 5);
    const size_t obase1 = (size_t)(b0 + 1) * TT * HH + (g << 5);
    const int slotbase = ((pair << 3) + g) << 1;          // *64 packets

    for (int chunk = 0; chunk < TT / TC; ++chunk) {
        const int t0 = chunk * TC;

        #pragma unroll
        for (int r = 0; r < 2; ++r) {
            const float4 xv = ((const float4*)(X + ((size_t)(b0 + r) * TT + t0) * DD))[tid];
            ((uint2*)Xs)[r * 512 + tid] = make_uint2(pkf16(xv.x, xv.y), pkf16(xv.z, xv.w));
        }
        bar_lgkm();

        {
            const int p = s >> 1, th = s & 1;
            float acc[8];
            #pragma unroll
            for (int t = 0; t < 8; ++t) acc[t] = bc;
            #pragma unroll
            for (int k8 = 0; k8 < 16; ++k8) {
                const uint4 w4 = Wlds4[c * 16 + (k8 ^ (c & 15))];
                #pragma unroll
                for (int t = 0; t < 8; ++t) {
                    const uint4 xg = *(const uint4*)((const char*)Xs +
                                     ((p * 16 + th * 8 + t) << 8) + (k8 << 4));
                    acc[t] = FDOT2(u2h(xg.x), u2h(w4.x), acc[t]);
                    acc[t] = FDOT2(u2h(xg.y), u2h(w4.y), acc[t]);
                    acc[t] = FDOT2(u2h(xg.z), u2h(w4.z), acc[t]);
                    acc[t] = FDOT2(u2h(xg.w), u2h(w4.w), acc[t]);
                }
            }
            #pragma unroll
            for (int t = 0; t < 8; ++t) xw[p][th * 8 + t][c] = acc[t];
        }
        bar_lgkm();

        for (int tt2 = 0; tt2 < TC; ++tt2) {
            const int tau = t0 + tt2;

            // ===== slot1: phase A for b0 =====
            {
                float a = (s == 0) ? xw[0][tt2][c] : 0.0f;
                #pragma unroll
                for (int ii = 0; ii < 8; ++ii) {
                    const uint4 ug = Ulds4[c * 32 + ((s * 8 + ii) ^ (c & 31))];
                    const uint4 hg = *(const uint4*)((const char*)hsh + (s << 7) + (ii << 4));
                    a = FDOT2(u2h(ug.x), u2h(hg.x), a);
                    a = FDOT2(u2h(ug.y), u2h(hg.y), a);
                    a = FDOT2(u2h(ug.z), u2h(hg.z), a);
                    a = FDOT2(u2h(ug.w), u2h(hg.w), a);
                }
                gvp[s][c] = a;
            }
            bar_lgkm();

            // ===== slot2: gates b0 + publish P0(tau+1)  ||  poll P1(tau) ====
            if (wave == 0) {
                if (lane < 32) {
                    const int j = lane;
                    float gi = 0.f, gf = 0.f, gg = 0.f, go = 0.f;
                    #pragma unroll
                    for (int q = 0; q < 4; ++q) {
                        gi += gvp[q][j];       gf += gvp[q][32 + j];
                        gg += gvp[q][64 + j];  go += gvp[q][96 + j];
                    }
                    const float it = sigf(gi), ft = sigf(gf);
                    const float gt = tanh_fast(gg), ot = sigf(go);
                    c_reg0 = fmaf(ft, c_reg0, it * gt);
                    const float hn = ot * tanh_fast(c_reg0);
                    h_last0 = hn;
                    const unsigned long long pkt =
                        ((unsigned long long)(unsigned)(tau + 1) << 32) |
                        (unsigned long long)__float_as_uint(hn);
                    const size_t idx = (size_t)(slotbase + ((tau + 1) & 1)) * 64 + j;
                    store_l2(&mbx2[idx], pkt);
                    __hip_atomic_store(&mbxa[idx], pkt,
                                       __ATOMIC_RELAXED, __HIP_MEMORY_SCOPE_AGENT);
                    out[obase0 + (size_t)tau * HH + j] = hn;
                    hsh[(g << 5) + j] = f16b(hn);
                }
            } else if (tau >= 1 && lane < 32) {
                const int pg = (g + wave) & 7;
                const size_t idx = (size_t)((((pair << 3) + pg) << 1) + (tau & 1)) * 64 + 32 + lane;
                unsigned long long v; bool got = false;
                for (int i = 0; i < 48; ++i) {
                    v = load_l2(&mbx2[idx]);
                    if ((unsigned)(v >> 32) == (unsigned)tau) { got = true; break; }
                }
                if (!got) {
                    int spins = 0;
                    do {
                        v = __hip_atomic_load(&mbxa[idx], __ATOMIC_RELAXED,
                                              __HIP_MEMORY_SCOPE_AGENT);
                        if (++spins > (1 << 20)) break;  // anti-hang
                    } while ((unsigned)(v >> 32) != (unsigned)tau);
                }
                hsh[256 + (pg << 5) + lane] = f16b(__uint_as_float((unsigned)v));
            }
            bar_lgkm();

            // ===== slot3: phase A for b1 =====
            {
                float a = (s == 0) ? xw[1][tt2][c] : 0.0f;
                #pragma unroll
                for (int ii = 0; ii < 8; ++ii) {
                    const uint4 ug = Ulds4[c * 32 + ((s * 8 + ii) ^ (c & 31))];
                    const uint4 hg = *(const uint4*)((const char*)hsh + 512 + (s << 7) + (ii << 4));
                    a = FDOT2(u2h(ug.x), u2h(hg.x), a);
                    a = FDOT2(u2h(ug.y), u2h(hg.y), a);
                    a = FDOT2(u2h(ug.z), u2h(hg.z), a);
                    a = FDOT2(u2h(ug.w), u2h(hg.w), a);
                }
                gvp[s][c] = a;
            }
            bar_lgkm();

            // ===== slot4: gates b1 + publish P1(tau+1)  ||  poll P0(tau+1) ==
            if (wave == 0) {
                if (lane < 32) {
                    const int j = lane;
                    float gi = 0.f, gf = 0.f, gg = 0.f, go = 0.f;
                    #pragma unroll
                    for (int q = 0; q < 4; ++q) {
                        gi += gvp[q][j];       gf += gvp[q][32 + j];
                        gg += gvp[q][64 + j];  go += gvp[q][96 + j];
                    }
                    const float it = sigf(gi), ft = sigf(gf);
                    const float gt = tanh_fast(gg), ot = sigf(go);
                    c_reg1 = fmaf(ft, c_reg1, it * gt);
                    const float hn = ot * tanh_fast(c_reg1);
                    h_last1 = hn;
                    const unsigned long long pkt =
                        ((unsigned long long)(unsigned)(tau + 1) << 32) |
                        (unsigned long long)__float_as_uint(hn);
                    const size_t idx = (size_t)(slotbase + ((tau + 1) & 1)) * 64 + 32 + j;
                    store_l2(&mbx2[idx], pkt);
                    __hip_atomic_store(&mbxa[idx], pkt,
                                       __ATOMIC_RELAXED, __HIP_MEMORY_SCOPE_AGENT);
                    out[obase1 + (size_t)tau * HH + j] = hn;
                    hsh[256 + (g << 5) + j] = f16b(hn);
                }
            } else if (tau < TT - 1 && lane < 32) {
                const int pg = (g + wave) & 7;
                const size_t idx = (size_t)((((pair << 3) + pg) << 1) + ((tau + 1) & 1)) * 64 + lane;
                unsigned long long v; bool got = false;
                for (int i = 0; i < 48; ++i) {
                    v = load_l2(&mbx2[idx]);
                    if ((unsigned)(v >> 32) == (unsigned)(tau + 1)) { got = true; break; }
                }
                if (!got) {
                    int spins = 0;
                    do {
                        v = __hip_atomic_load(&mbxa[idx], __ATOMIC_RELAXED,
                                              __HIP_MEMORY_SCOPE_AGENT);
                        if (++spins > (1 << 20)) break;  // anti-hang
                    } while ((unsigned)(v >> 32) != (unsigned)(tau + 1));
                }
                hsh[(pg << 5) + lane] = f16b(__uint_as_float((unsigned)v));
            }
            bar_lgkm();
        }
    }

    if (wave == 0 && lane < 32) {
        const size_t base = (size_t)BB * TT * HH;
        out[base + (size_t)b0 * HH + (g << 5) + lane] = h_last0;
        out[base + (size_t)(b0 + 1) * HH + (g << 5) + lane] = h_last1;
        out[base + (size_t)BB * HH + (size_t)b0 * HH + (g << 5) + lane] = c_reg0;
        out[base + (size_t)BB * HH + (size_t)(b0 + 1) * HH + (g << 5) + lane] = c_reg1;
    }
}

// ==================== R7 fallback (agent-only mailbox) ======================
extern "C" __global__ void __launch_bounds__(512, 2)
lstm_pipe(const float* __restrict__ X, const unsigned short* __restrict__ Upack,
          const unsigned short* __restrict__ Wpack, const float* __restrict__ bias,
          const float* __restrict__ h0, const float* __restrict__ c0,
          unsigned long long* __restrict__ hglob, float* __restrict__ out)
{
    __shared__ __align__(16) uint4 Ulds4[128 * 32];
    __shared__ __align__(16) uint4 Wlds4[128 * 16];
    __shared__ float xw[2][TC][128];
    __shared__ __align__(16) unsigned short Xs[2 * TC * DD];
    __shared__ float gvp[4][128];
    __shared__ __align__(16) unsigned short hsh[2 * HH];

    const int pair = blockIdx.x & 31;
    const int g = blockIdx.x >> 5;
    const int b0 = pair * 2;
    const int tid = threadIdx.x;
    const int wave = tid >> 6, lane = tid & 63;
    const int c = tid & 127, s = tid >> 7;

    {
        const uint4* Usrc = (const uint4*)(Upack + (size_t)g * 32768);
        #pragma unroll
        for (int i = 0; i < 8; ++i) {
            const int idx = i * 512 + tid;
            const int cc = idx >> 5, gr = idx & 31;
            Ulds4[cc * 32 + (gr ^ (cc & 31))] = Usrc[idx];
        }
        const uint4* Wsrc = (const uint4*)(Wpack + (size_t)g * 16384);
        #pragma unroll
        for (int i = 0; i < 4; ++i) {
            const int idx = i * 512 + tid;
            const int cc = idx >> 4, gr = idx & 15;
            Wlds4[cc * 16 + (gr ^ (cc & 15))] = Wsrc[idx];
        }
    }
    hsh[tid] = f16b(h0[(size_t)(b0 + (tid >> 8)) * HH + (tid & 255)]);
    float c_reg0 = 0.0f, c_reg1 = 0.0f, h_last0 = 0.0f, h_last1 = 0.0f;
    if (wave == 0 && lane < 32) {
        c_reg0 = c0[(size_t)b0 * HH + (g << 5) + lane];
        c_reg1 = c0[(size_t)(b0 + 1) * HH + (g << 5) + lane];
        h_last0 = h0[(size_t)b0 * HH + (g << 5) + lane];
        h_last1 = h0[(size_t)(b0 + 1) * HH + (g << 5) + lane];
    }
    const float bc = bias[((c >> 5) << 8) + (g << 5) + (c & 31)];
    __syncthreads();

    const size_t obase0 = (size_t)b0 * TT * HH + (g << 5);
    const size_t obase1 = (size_t)(b0 + 1) * TT * HH + (g << 5);
    const int slotbase = ((pair << 3) + g) << 1;

    for (int chunk = 0; chunk < TT / TC; ++chunk) {
        const int t0 = chunk * TC;
        #pragma unroll
        for (int r = 0; r < 2; ++r) {
            const float4 xv = ((const float4*)(X + ((size_t)(b0 + r) * TT + t0) * DD))[tid];
            ((uint2*)Xs)[r * 512 + tid] = make_uint2(pkf16(xv.x, xv.y), pkf16(xv.z, xv.w));
        }
        bar_lgkm();
        {
            const int p = s >> 1, th = s & 1;
            float acc[8];
            #pragma unroll
            for (int t = 0; t < 8; ++t) acc[t] = bc;
            #pragma unroll
            for (int k8 = 0; k8 < 16; ++k8) {
                const uint4 w4 = Wlds4[c * 16 + (k8 ^ (c & 15))];
                #pragma unroll
                for (int t = 0; t < 8; ++t) {
                    const uint4 xg = *(const uint4*)((const char*)Xs +
                                     ((p * 16 + th * 8 + t) << 8) + (k8 << 4));
                    acc[t] = FDOT2(u2h(xg.x), u2h(w4.x), acc[t]);
                    acc[t] = FDOT2(u2h(xg.y), u2h(w4.y), acc[t]);
                    acc[t] = FDOT2(u2h(xg.z), u2h(w4.z), acc[t]);
                    acc[t] = FDOT2(u2h(xg.w), u2h(w4.w), acc[t]);
                }
            }
            #pragma unroll
            for (int t = 0; t < 8; ++t) xw[p][th * 8 + t][c] = acc[t];
        }
        bar_lgkm();

        for (int tt2 = 0; tt2 < TC; ++tt2) {
            const int tau = t0 + tt2;
            {
                float a = (s == 0) ? xw[0][tt2][c] : 0.0f;
                #pragma unroll
                for (int ii = 0; ii < 8; ++ii) {
                    const uint4 ug = Ulds4[c * 32 + ((s * 8 + ii) ^ (c & 31))];
                    const uint4 hg = *(const uint4*)((const char*)hsh + (s << 7) + (ii << 4));
                    a = FDOT2(u2h(ug.x), u2h(hg.x), a);
                    a = FDOT2(u2h(ug.y), u2h(hg.y), a);
                    a = FDOT2(u2h(ug.z), u2h(hg.z), a);
                    a = FDOT2(u2h(ug.w), u2h(hg.w), a);
                }
                gvp[s][c] = a;
            }
            bar_lgkm();

            if (wave == 0) {
                if (lane < 32) {
                    const int j = lane;
                    float gi = 0.f, gf = 0.f, gg = 0.f, go = 0.f;
                    #pragma unroll
                    for (int q = 0; q < 4; ++q) {
                        gi += gvp[q][j];       gf += gvp[q][32 + j];
                        gg += gvp[q][64 + j];  go += gvp[q][96 + j];
                    }
                    const float it = sigf(gi), ft = sigf(gf);
                    const float gt = tanh_fast(gg), ot = sigf(go);
                    c_reg0 = fmaf(ft, c_reg0, it * gt);
                    const float hn = ot * tanh_fast(c_reg0);
                    h_last0 = hn;
                    const unsigned long long pkt =
                        ((unsigned long long)(unsigned)(tau + 1) << 32) |
                        (unsigned long long)__float_as_uint(hn);
                    __hip_atomic_store(&hglob[(size_t)(slotbase + ((tau + 1) & 1)) * 64 + j],
                                       pkt, __ATOMIC_RELAXED, __HIP_MEMORY_SCOPE_AGENT);
                    out[obase0 + (size_t)tau * HH + j] = hn;
                    hsh[(g << 5) + j] = f16b(hn);
                }
            } else if (tau >= 1 && lane < 32) {
                const int pg = (g + wave) & 7;
                const unsigned long long* q =
                    &hglob[(size_t)((((pair << 3) + pg) << 1) + (tau & 1)) * 64 + 32 + lane];
                unsigned long long v; int spins = 0;
                do {
                    v = __hip_atomic_load(q, __ATOMIC_RELAXED, __HIP_MEMORY_SCOPE_AGENT);
                    if (++spins > (1 << 20)) break;
                } while ((unsigned)(v >> 32) != (unsigned)tau);
                hsh[256 + (pg << 5) + lane] = f16b(__uint_as_float((unsigned)v));
            }
            bar_lgkm();

            {
                float a = (s == 0) ? xw[1][tt2][c] : 0.0f;
                #pragma unroll
                for (int ii = 0; ii < 8; ++ii) {
                    const uint4 ug = Ulds4[c * 32 + ((s * 8 + ii) ^ (c & 31))];
                    const uint4 hg = *(const uint4*)((const char*)hsh + 512 + (s << 7) + (ii << 4));
                    a = FDOT2(u2h(ug.x), u2h(hg.x), a);
                    a = FDOT2(u2h(ug.y), u2h(hg.y), a);
                    a = FDOT2(u2h(ug.z), u2h(hg.z), a);
                    a = FDOT2(u2h(ug.w), u2h(hg.w), a);
                }
                gvp[s][c] = a;
            }
            bar_lgkm();

            if (wave == 0) {
                if (lane < 32) {
                    const int j = lane;
                    float gi = 0.f, gf = 0.f, gg = 0.f, go = 0.f;
                    #pragma unroll
                    for (int q = 0; q < 4; ++q) {
                        gi += gvp[q][j];       gf += gvp[q][32 + j];
                        gg += gvp[q][64 + j];  go += gvp[q][96 + j];
                    }
                    const float it = sigf(gi), ft = sigf(gf);
                    const float gt = tanh_fast(gg), ot = sigf(go);
                    c_reg1 = fmaf(ft, c_reg1, it * gt);
                    const float hn = ot * tanh_fast(c_reg1);
                    h_last1 = hn;
                    const unsigned long long pkt =
                        ((unsigned long long)(unsigned)(tau + 1) << 32) |
                        (unsigned long long)__float_as_uint(hn);
                    __hip_atomic_store(&hglob[(size_t)(slotbase + ((tau + 1) & 1)) * 64 + 32 + j],
                                       pkt, __ATOMIC_RELAXED, __HIP_MEMORY_SCOPE_AGENT);
                    out[obase1 + (size_t)tau * HH + j] = hn;
                    hsh[256 + (g << 5) + j] = f16b(hn);
                }
            } else if (tau < TT - 1 && lane < 32) {
                const int pg = (g + wave) & 7;
                const unsigned long long* q =
                    &hglob[(size_t)((((pair << 3) + pg) << 1) + ((tau + 1) & 1)) * 64 + lane];
                unsigned long long v; int spins = 0;
                do {
                    v = __hip_atomic_load(q, __ATOMIC_RELAXED, __HIP_MEMORY_SCOPE_AGENT);
                    if (++spins > (1 << 20)) break;
                } while ((unsigned)(v >> 32) != (unsigned)(tau + 1));
                hsh[(pg << 5) + lane] = f16b(__uint_as_float((unsigned)v));
            }
            bar_lgkm();
        }
    }

    if (wave == 0 && lane < 32) {
        const size_t base = (size_t)BB * TT * HH;
        out[base + (size_t)b0 * HH + (g << 5) + lane] = h_last0;
        out[base + (size_t)(b0 + 1) * HH + (g << 5) + lane] = h_last1;
        out[base + (size_t)BB * HH + (size_t)b0 * HH + (g << 5) + lane] = c_reg0;
        out[base + (size_t)BB * HH + (size_t)(b0 + 1) * HH + (g << 5) + lane] = c_reg1;
    }
}

// ===================== R2 fallback (f32, no workspace) ======================
extern "C" __global__ void __launch_bounds__(512)
lstm_persist(const float* __restrict__ X, const float* __restrict__ W,
             const float* __restrict__ U, const float* __restrict__ bias,
             const float* __restrict__ h0, const float* __restrict__ c0,
             float* __restrict__ out)
{
    __shared__ float xw[TC][G4];
    __shared__ float Xs[TC][DD];
    __shared__ float hsh[HH];
    __shared__ float gv[G4];

    const int b = blockIdx.x;
    const int tid = threadIdx.x;
    const float2* __restrict__ U2 = reinterpret_cast<const float2*>(U);
    const float2* __restrict__ W2 = reinterpret_cast<const float2*>(W);

    float c_reg = 0.0f;
    if (tid < HH) { hsh[tid] = h0[b * HH + tid]; c_reg = c0[b * HH + tid]; }
    const float2 bs = reinterpret_cast<const float2*>(bias)[tid];
    __syncthreads();

    for (int chunk = 0; chunk < TT / TC; ++chunk) {
        const int t0 = chunk * TC;
        {
            const float4* src = reinterpret_cast<const float4*>(X + ((size_t)b * TT + t0) * DD);
            float4* dst = reinterpret_cast<float4*>(&Xs[0][0]);
            for (int i = tid; i < TC * DD / 4; i += 512) dst[i] = src[i];
        }
        __syncthreads();
        float acc0[TC], acc1[TC];
        #pragma unroll
        for (int t = 0; t < TC; ++t) { acc0[t] = bs.x; acc1[t] = bs.y; }
        for (int kk = 0; kk < DD; kk += 4) {
            const float2 w0 = W2[(size_t)(kk + 0) * (G4 / 2) + tid];
            const float2 w1 = W2[(size_t)(kk + 1) * (G4 / 2) + tid];
            const float2 w2 = W2[(size_t)(kk + 2) * (G4 / 2) + tid];
            const float2 w3 = W2[(size_t)(kk + 3) * (G4 / 2) + tid];
            #pragma unroll
            for (int t = 0; t < TC; ++t) {
                const float4 xv = *reinterpret_cast<const float4*>(&Xs[t][kk]);
                acc0[t] = fmaf(xv.x, w0.x, acc0[t]); acc1[t] = fmaf(xv.x, w0.y, acc1[t]);
                acc0[t] = fmaf(xv.y, w1.x, acc0[t]); acc1[t] = fmaf(xv.y, w1.y, acc1[t]);
                acc0[t] = fmaf(xv.z, w2.x, acc0[t]); acc1[t] = fmaf(xv.z, w2.y, acc1[t]);
                acc0[t] = fmaf(xv.w, w3.x, acc0[t]); acc1[t] = fmaf(xv.w, w3.y, acc1[t]);
            }
        }
        #pragma unroll
        for (int t = 0; t < TC; ++t)
            *reinterpret_cast<float2*>(&xw[t][2 * tid]) = make_float2(acc0[t], acc1[t]);
        __syncthreads();

        for (int t = 0; t < TC; ++t) {
            const float2 x2 = *reinterpret_cast<const float2*>(&xw[t][2 * tid]);
            float a0 = x2.x, a1 = x2.y;
            #pragma unroll 4
            for (int k = 0; k < HH; k += 4) {
                const float4 hk = *reinterpret_cast<const float4*>(&hsh[k]);
                const float2 u0 = U2[(size_t)(k + 0) * (G4 / 2) + tid];
                const float2 u1 = U2[(size_t)(k + 1) * (G4 / 2) + tid];
                const float2 u2 = U2[(size_t)(k + 2) * (G4 / 2) + tid];
                const float2 u3 = U2[(size_t)(k + 3) * (G4 / 2) + tid];
                a0 = fmaf(hk.x, u0.x, a0); a1 = fmaf(hk.x, u0.y, a1);
                a0 = fmaf(hk.y, u1.x, a0); a1 = fmaf(hk.y, u1.y, a1);
                a0 = fmaf(hk.z, u2.x, a0); a1 = fmaf(hk.z, u2.y, a1);
                a0 = fmaf(hk.w, u3.x, a0); a1 = fmaf(hk.w, u3.y, a1);
            }
            *reinterpret_cast<float2*>(&gv[2 * tid]) = make_float2(a0, a1);
            __syncthreads();
            if (tid < HH) {
                const float it = sigf(gv[tid]);
                const float ft = sigf(gv[tid + HH]);
                const float gt = tanh_fast(gv[tid + 2 * HH]);
                const float ot = sigf(gv[tid + 3 * HH]);
                c_reg = fmaf(ft, c_reg, it * gt);
                const float hn = ot * tanh_fast(c_reg);
                hsh[tid] = hn;
                out[((size_t)b * TT + (t0 + t)) * HH + tid] = hn;
            }
            __syncthreads();
        }
    }
    if (tid < HH) {
        const size_t base = (size_t)BB * TT * HH;
        out[base + (size_t)b * HH + tid] = hsh[tid];
        out[base + (size_t)BB * HH + (size_t)b * HH + tid] = c_reg;
    }
}

extern "C" void kernel_launch(void* const* d_in, const int* in_sizes, int n_in,
                              void* d_out, int out_size, void* d_ws, size_t ws_size,
                              hipStream_t stream) {
    const float* X    = (const float*)d_in[0];
    const float* W    = (const float*)d_in[1];
    const float* U    = (const float*)d_in[2];
    const float* bias = (const float*)d_in[3];
    const float* h0   = (const float*)d_in[4];
    const float* c0   = (const float*)d_in[5];
    float* out = (float*)d_out;
    (void)in_sizes; (void)n_in; (void)out_size;

    const size_t upk = 512 * 1024;     // Upack f16 [8][128][256]
    const size_t wpk = 256 * 1024;     // Wpack f16 [8][128][128]
    const size_t mbx = 256 * 1024;     // one mailbox: u64 [32][8][2][2][32]

    // --- R9 path: 1.25 MB workspace (dual mailbox) ---
    if (ws_size >= upk + wpk + 2 * mbx) {
        unsigned short* Upack = (unsigned short*)d_ws;
        unsigned short* Wpack = (unsigned short*)((char*)d_ws + upk);
        unsigned long long* mbx2 = (unsigned long long*)((char*)d_ws + upk + wpk);
        unsigned long long* mbxa = (unsigned long long*)((char*)d_ws + upk + wpk + mbx);
        zero_hglob<<<dim3(256), dim3(256), 0, stream>>>(mbx2);  // both mailboxes
        pack_slices<<<dim3(8, 4), dim3(128), 0, stream>>>(U, Upack, 256);
        pack_slices<<<dim3(8, 2), dim3(128), 0, stream>>>(W, Wpack, 128);
        lstm_pipe2<<<dim3(256), dim3(512), 0, stream>>>(
            X, Upack, Wpack, bias, h0, c0, mbx2, mbxa, out);
        return;
    }

    // --- R7 fallback: 1 MB workspace ---
    if (ws_size >= upk + wpk + mbx) {
        unsigned short* Upack = (unsigned short*)d_ws;
        unsigned short* Wpack = (unsigned short*)((char*)d_ws + upk);
        unsigned long long* hglob = (unsigned long long*)((char*)d_ws + upk + wpk);
        zero_hglob<<<dim3(128), dim3(256), 0, stream>>>(hglob);
        pack_slices<<<dim3(8, 4), dim3(128), 0, stream>>>(U, Upack, 256);
        pack_slices<<<dim3(8, 2), dim3(128), 0, stream>>>(W, Wpack, 128);
        lstm_pipe<<<dim3(256), dim3(512), 0, stream>>>(
            X, Upack, Wpack, bias, h0, c0, hglob, out);
        return;
    }

    // --- R2 fallback: no workspace ---
    lstm_persist<<<dim3(BB), dim3(512), 0, stream>>>(X, W, U, bias, h0, c0, out);
}

// Round 10
// 3567.883 us; speedup vs baseline: 6.4094x; 6.4094x over previous
//
#include <hip/hip_runtime.h>
#include <hip/hip_bf16.h>

// SpatialLSTM: B=64, T=2048, D=128, H=256 (4H=1024)
// R10: back to the proven LLC fused-packet protocol (R7), restructured:
//  - ONE fused phase-A per step: both batches' dots share each U LDS read
//    (R7 read the 64KB U-slice twice per step -- once per batch).
//  - ONE exchange per step: wave0's 64 lanes = 32 cols x 2 batches; packets
//    carry BOTH batches' h as 2xf16 in one u64 {ctr, h_b1, h_b0} -> half the
//    mailbox traffic. 2 barriers/step (was 4).
//  - pollers s_sleep briefly so the first LLC probe lands after packet flight.
// R9's cross-XCD L2 mailbox is dead (L2s cache stale lines; LLC is the only
// coherence point). Parity double-buffer WAR-safety unchanged.
#define BB 64
#define TT 2048
#define DD 128
#define HH 256
#define G4 1024
#define TC 16

typedef _Float16 half2_t __attribute__((ext_vector_type(2)));

#if __has_builtin(__builtin_amdgcn_fdot2)
#define FDOT2(a, b, c) __builtin_amdgcn_fdot2((a), (b), (c), false)
#else
__device__ __forceinline__ float FDOT2(half2_t a, half2_t b, float c) {
    return c + (float)a[0] * (float)b[0] + (float)a[1] * (float)b[1];
}
#endif

__device__ __forceinline__ half2_t u2h(unsigned int u) {
    union { unsigned int u; half2_t h; } x; x.u = u; return x.h;
}
__device__ __forceinline__ unsigned int pkf16(float a, float b) {
    union { _Float16 h[2]; unsigned int u; } x;
    x.h[0] = (_Float16)a; x.h[1] = (_Float16)b; return x.u;
}
__device__ __forceinline__ unsigned short f16b(float a) {
    union { _Float16 h; unsigned short u; } x; x.h = (_Float16)a; return x.u;
}
__device__ __forceinline__ float sigf(float x) {
    return 1.0f / (1.0f + __expf(-x));
}
__device__ __forceinline__ float tanh_fast(float x) {
    return 1.0f - 2.0f / (__expf(2.0f * x) + 1.0f);
}
// LDS-ordering-only barrier (no vmcnt store-ack drain; peers poll the LLC)
__device__ __forceinline__ void bar_lgkm() {
    asm volatile("s_waitcnt lgkmcnt(0)\n\ts_barrier" ::: "memory");
}

// ---- zero the packet mailbox (counters must start < 1 every launch) ----
__global__ void zero_hglob(unsigned long long* hglob) {
    hglob[blockIdx.x * 256 + threadIdx.x] = 0ull;
}

// ---- pack slice-columns: src f32 [K][1024] -> dst f16 [8 slices][128 c][K]
// local col c of slice g <-> global gate col (c>>5)*256 + g*32 + (c&31)
__global__ void __launch_bounds__(128)
pack_slices(const float* __restrict__ src, unsigned short* __restrict__ dst, int K)
{
    const int g = blockIdx.x, kb = blockIdx.y, c = threadIdx.x;
    const int gc = ((c >> 5) << 8) + (g << 5) + (c & 31);
    unsigned int* d32 = (unsigned int*)dst;
    const int dbase = ((g << 7) + c) * K + kb * 64;     // half index, even
    for (int kk = 0; kk < 64; kk += 2) {
        const float a = src[(size_t)(kb * 64 + kk) * G4 + gc];
        const float b = src[(size_t)(kb * 64 + kk + 1) * G4 + gc];
        d32[(dbase + kk) >> 1] = pkf16(a, b);
    }
}

// ============================ R10 main kernel ===============================
// grid 256: pair = blk&31 (2 batches), g = blk>>5 (slice of 32 h-cols)
extern "C" __global__ void __launch_bounds__(512, 2)
lstm_fuse(const float* __restrict__ X, const unsigned short* __restrict__ Upack,
          const unsigned short* __restrict__ Wpack, const float* __restrict__ bias,
          const float* __restrict__ h0, const float* __restrict__ c0,
          unsigned long long* __restrict__ hglob, float* __restrict__ out)
{
    __shared__ __align__(16) uint4 Ulds4[128 * 32];      // 64 KB, swizzled
    __shared__ __align__(16) uint4 Wlds4[128 * 16];      // 32 KB, swizzled
    __shared__ float xw[2][TC][128];                     // 16 KB
    __shared__ __align__(16) unsigned short Xs[2 * TC * DD]; // 8 KB (f16)
    __shared__ float gvp[2][4][128];                     // 4 KB partials
    __shared__ __align__(16) unsigned short hsh[2 * HH]; // 1 KB
    // total 125 KB

    const int pair = blockIdx.x & 31;
    const int g = blockIdx.x >> 5;
    const int b0 = pair * 2;
    const int tid = threadIdx.x;
    const int wave = tid >> 6, lane = tid & 63;
    const int c = tid & 127, s = tid >> 7;               // local col, k-quarter

    // ---- stage U-slice (swizzle granule gr^(c&31)) and W-slice (gr^(c&15)) --
    {
        const uint4* Usrc = (const uint4*)(Upack + (size_t)g * 32768);
        #pragma unroll
        for (int i = 0; i < 8; ++i) {
            const int idx = i * 512 + tid;               // cc*32 + gr
            const int cc = idx >> 5, gr = idx & 31;
            Ulds4[cc * 32 + (gr ^ (cc & 31))] = Usrc[idx];
        }
        const uint4* Wsrc = (const uint4*)(Wpack + (size_t)g * 16384);
        #pragma unroll
        for (int i = 0; i < 4; ++i) {
            const int idx = i * 512 + tid;               // cc*16 + gr
            const int cc = idx >> 4, gr = idx & 15;
            Wlds4[cc * 16 + (gr ^ (cc & 15))] = Wsrc[idx];
        }
    }
    hsh[tid] = f16b(h0[(size_t)(b0 + (tid >> 8)) * HH + (tid & 255)]);
    float c_reg = 0.0f, h_last = 0.0f;
    if (wave == 0) {
        const int p = lane >> 5, j = lane & 31;
        c_reg = c0[(size_t)(b0 + p) * HH + (g << 5) + j];
        h_last = h0[(size_t)(b0 + p) * HH + (g << 5) + j];
    }
    const float bc = bias[((c >> 5) << 8) + (g << 5) + (c & 31)];
    __syncthreads();

    const size_t obase0 = (size_t)b0 * TT * HH + (g << 5);
    const size_t obase1 = (size_t)(b0 + 1) * TT * HH + (g << 5);
    const int slotbase = ((pair << 3) + g) << 1;          // *32 packets

    for (int chunk = 0; chunk < TT / TC; ++chunk) {
        const int t0 = chunk * TC;

        // ---- stage X chunk for 2 batches (f32 -> f16 pairs) ----
        #pragma unroll
        for (int r = 0; r < 2; ++r) {
            const float4 xv = ((const float4*)(X + ((size_t)(b0 + r) * TT + t0) * DD))[tid];
            ((uint2*)Xs)[r * 512 + tid] = make_uint2(pkf16(xv.x, xv.y), pkf16(xv.z, xv.w));
        }
        bar_lgkm();

        // ---- xw[p][t][c] = X@Wslice + bias; thread (c,s): p=s>>1, th=s&1 ----
        {
            const int p = s >> 1, th = s & 1;
            float acc[8];
            #pragma unroll
            for (int t = 0; t < 8; ++t) acc[t] = bc;
            #pragma unroll
            for (int k8 = 0; k8 < 16; ++k8) {
                const uint4 w4 = Wlds4[c * 16 + (k8 ^ (c & 15))];
                #pragma unroll
                for (int t = 0; t < 8; ++t) {
                    const uint4 xg = *(const uint4*)((const char*)Xs +
                                     ((p * 16 + th * 8 + t) << 8) + (k8 << 4));
                    acc[t] = FDOT2(u2h(xg.x), u2h(w4.x), acc[t]);
                    acc[t] = FDOT2(u2h(xg.y), u2h(w4.y), acc[t]);
                    acc[t] = FDOT2(u2h(xg.z), u2h(w4.z), acc[t]);
                    acc[t] = FDOT2(u2h(xg.w), u2h(w4.w), acc[t]);
                }
            }
            #pragma unroll
            for (int t = 0; t < 8; ++t) xw[p][th * 8 + t][c] = acc[t];
        }
        bar_lgkm();

        // ---- TC recurrent steps: { fused A (both batches) | one exchange } --
        for (int tt2 = 0; tt2 < TC; ++tt2) {
            const int tau = t0 + tt2;

            // ===== fused phase A: U read once, 2 fdot2 per fragment =====
            {
                float a0 = (s == 0) ? xw[0][tt2][c] : 0.0f;
                float a1 = (s == 0) ? xw[1][tt2][c] : 0.0f;
                #pragma unroll
                for (int ii = 0; ii < 8; ++ii) {
                    const uint4 ug = Ulds4[c * 32 + ((s * 8 + ii) ^ (c & 31))];
                    const uint4 hg0 = *(const uint4*)((const char*)hsh + (s << 7) + (ii << 4));
                    const uint4 hg1 = *(const uint4*)((const char*)hsh + 512 + (s << 7) + (ii << 4));
                    a0 = FDOT2(u2h(ug.x), u2h(hg0.x), a0);
                    a1 = FDOT2(u2h(ug.x), u2h(hg1.x), a1);
                    a0 = FDOT2(u2h(ug.y), u2h(hg0.y), a0);
                    a1 = FDOT2(u2h(ug.y), u2h(hg1.y), a1);
                    a0 = FDOT2(u2h(ug.z), u2h(hg0.z), a0);
                    a1 = FDOT2(u2h(ug.z), u2h(hg1.z), a1);
                    a0 = FDOT2(u2h(ug.w), u2h(hg0.w), a0);
                    a1 = FDOT2(u2h(ug.w), u2h(hg1.w), a1);
                }
                gvp[0][s][c] = a0;
                gvp[1][s][c] = a1;
            }
            bar_lgkm();

            // ===== exchange: wave0 gates both batches + publish dual-f16
            //        packets; waves 1-7 poll the 7 peers =====
            const int par = (tau + 1) & 1;
            if (wave == 0) {
                const int p = lane >> 5, j = lane & 31;
                const float* gv = &gvp[p][0][0];
                float gi = 0.f, gf = 0.f, gg = 0.f, go = 0.f;
                #pragma unroll
                for (int q = 0; q < 4; ++q) {
                    gi += gv[q * 128 + j];       gf += gv[q * 128 + 32 + j];
                    gg += gv[q * 128 + 64 + j];  go += gv[q * 128 + 96 + j];
                }
                const float it = sigf(gi), ft = sigf(gf);
                const float gt = tanh_fast(gg), ot = sigf(go);
                c_reg = fmaf(ft, c_reg, it * gt);
                const float hn = ot * tanh_fast(c_reg);
                h_last = hn;
                const unsigned int hu = f16b(hn);
                const unsigned int lo = __shfl((int)hu, j);        // b0 col j
                const unsigned int hi = __shfl((int)hu, j + 32);   // b1 col j
                if (lane < 32) {
                    const unsigned long long pkt =
                        ((unsigned long long)(unsigned)(tau + 1) << 32) |
                        ((unsigned long long)hi << 16) | (unsigned long long)lo;
                    __hip_atomic_store(&hglob[(size_t)(slotbase + par) * 32 + j],
                                       pkt, __ATOMIC_RELAXED, __HIP_MEMORY_SCOPE_AGENT);
                }
                out[(p ? obase1 : obase0) + (size_t)tau * HH + j] = hn;
                hsh[(p << 8) + (g << 5) + j] = (unsigned short)hu;
            } else if (tau < TT - 1 && lane < 32) {
                const int pg = (g + wave) & 7;
                const unsigned long long* q =
                    &hglob[(size_t)((((pair << 3) + pg) << 1) + par) * 32 + lane];
                __builtin_amdgcn_s_sleep(2);   // let the publish flight land
                unsigned long long v; int spins = 0;
                do {
                    v = __hip_atomic_load(q, __ATOMIC_RELAXED, __HIP_MEMORY_SCOPE_AGENT);
                    if (++spins > (1 << 20)) break;      // anti-hang: fail fast
                } while ((unsigned)(v >> 32) != (unsigned)(tau + 1));
                hsh[(pg << 5) + lane] = (unsigned short)(v & 0xffff);
                hsh[256 + (pg << 5) + lane] = (unsigned short)((v >> 16) & 0xffff);
            }
            bar_lgkm();
        }
    }

    if (wave == 0) {
        const int p = lane >> 5, j = lane & 31;
        const size_t base = (size_t)BB * TT * HH;
        out[base + (size_t)(b0 + p) * HH + (g << 5) + j] = h_last;
        out[base + (size_t)BB * HH + (size_t)(b0 + p) * HH + (g << 5) + j] = c_reg;
    }
}

// ===================== R2 fallback (f32, no workspace) ======================
extern "C" __global__ void __launch_bounds__(512)
lstm_persist(const float* __restrict__ X, const float* __restrict__ W,
             const float* __restrict__ U, const float* __restrict__ bias,
             const float* __restrict__ h0, const float* __restrict__ c0,
             float* __restrict__ out)
{
    __shared__ float xw[TC][G4];
    __shared__ float Xs[TC][DD];
    __shared__ float hsh[HH];
    __shared__ float gv[G4];

    const int b = blockIdx.x;
    const int tid = threadIdx.x;
    const float2* __restrict__ U2 = reinterpret_cast<const float2*>(U);
    const float2* __restrict__ W2 = reinterpret_cast<const float2*>(W);

    float c_reg = 0.0f;
    if (tid < HH) { hsh[tid] = h0[b * HH + tid]; c_reg = c0[b * HH + tid]; }
    const float2 bs = reinterpret_cast<const float2*>(bias)[tid];
    __syncthreads();

    for (int chunk = 0; chunk < TT / TC; ++chunk) {
        const int t0 = chunk * TC;
        {
            const float4* src = reinterpret_cast<const float4*>(X + ((size_t)b * TT + t0) * DD);
            float4* dst = reinterpret_cast<float4*>(&Xs[0][0]);
            for (int i = tid; i < TC * DD / 4; i += 512) dst[i] = src[i];
        }
        __syncthreads();
        float acc0[TC], acc1[TC];
        #pragma unroll
        for (int t = 0; t < TC; ++t) { acc0[t] = bs.x; acc1[t] = bs.y; }
        for (int kk = 0; kk < DD; kk += 4) {
            const float2 w0 = W2[(size_t)(kk + 0) * (G4 / 2) + tid];
            const float2 w1 = W2[(size_t)(kk + 1) * (G4 / 2) + tid];
            const float2 w2 = W2[(size_t)(kk + 2) * (G4 / 2) + tid];
            const float2 w3 = W2[(size_t)(kk + 3) * (G4 / 2) + tid];
            #pragma unroll
            for (int t = 0; t < TC; ++t) {
                const float4 xv = *reinterpret_cast<const float4*>(&Xs[t][kk]);
                acc0[t] = fmaf(xv.x, w0.x, acc0[t]); acc1[t] = fmaf(xv.x, w0.y, acc1[t]);
                acc0[t] = fmaf(xv.y, w1.x, acc0[t]); acc1[t] = fmaf(xv.y, w1.y, acc1[t]);
                acc0[t] = fmaf(xv.z, w2.x, acc0[t]); acc1[t] = fmaf(xv.z, w2.y, acc1[t]);
                acc0[t] = fmaf(xv.w, w3.x, acc0[t]); acc1[t] = fmaf(xv.w, w3.y, acc1[t]);
            }
        }
        #pragma unroll
        for (int t = 0; t < TC; ++t)
            *reinterpret_cast<float2*>(&xw[t][2 * tid]) = make_float2(acc0[t], acc1[t]);
        __syncthreads();

        for (int t = 0; t < TC; ++t) {
            const float2 x2 = *reinterpret_cast<const float2*>(&xw[t][2 * tid]);
            float a0 = x2.x, a1 = x2.y;
            #pragma unroll 4
            for (int k = 0; k < HH; k += 4) {
                const float4 hk = *reinterpret_cast<const float4*>(&hsh[k]);
                const float2 u0 = U2[(size_t)(k + 0) * (G4 / 2) + tid];
                const float2 u1 = U2[(size_t)(k + 1) * (G4 / 2) + tid];
                const float2 u2 = U2[(size_t)(k + 2) * (G4 / 2) + tid];
                const float2 u3 = U2[(size_t)(k + 3) * (G4 / 2) + tid];
                a0 = fmaf(hk.x, u0.x, a0); a1 = fmaf(hk.x, u0.y, a1);
                a0 = fmaf(hk.y, u1.x, a0); a1 = fmaf(hk.y, u1.y, a1);
                a0 = fmaf(hk.z, u2.x, a0); a1 = fmaf(hk.z, u2.y, a1);
                a0 = fmaf(hk.w, u3.x, a0); a1 = fmaf(hk.w, u3.y, a1);
            }
            *reinterpret_cast<float2*>(&gv[2 * tid]) = make_float2(a0, a1);
            __syncthreads();
            if (tid < HH) {
                const float it = sigf(gv[tid]);
                const float ft = sigf(gv[tid + HH]);
                const float gt = tanh_fast(gv[tid + 2 * HH]);
                const float ot = sigf(gv[tid + 3 * HH]);
                c_reg = fmaf(ft, c_reg, it * gt);
                const float hn = ot * tanh_fast(c_reg);
                hsh[tid] = hn;
                out[((size_t)b * TT + (t0 + t)) * HH + tid] = hn;
            }
            __syncthreads();
        }
    }
    if (tid < HH) {
        const size_t base = (size_t)BB * TT * HH;
        out[base + (size_t)b * HH + tid] = hsh[tid];
        out[base + (size_t)BB * HH + (size_t)b * HH + tid] = c_reg;
    }
}

extern "C" void kernel_launch(void* const* d_in, const int* in_sizes, int n_in,
                              void* d_out, int out_size, void* d_ws, size_t ws_size,
                              hipStream_t stream) {
    const float* X    = (const float*)d_in[0];
    const float* W    = (const float*)d_in[1];
    const float* U    = (const float*)d_in[2];
    const float* bias = (const float*)d_in[3];
    const float* h0   = (const float*)d_in[4];
    const float* c0   = (const float*)d_in[5];
    float* out = (float*)d_out;
    (void)in_sizes; (void)n_in; (void)out_size;

    const size_t upk = 512 * 1024;     // Upack f16 [8][128][256]
    const size_t wpk = 256 * 1024;     // Wpack f16 [8][128][128]
    const size_t mbx = 128 * 1024;     // mailbox u64 [32][8][2][32]

    // --- R10 path: 896 KB workspace ---
    if (ws_size >= upk + wpk + mbx) {
        unsigned short* Upack = (unsigned short*)d_ws;
        unsigned short* Wpack = (unsigned short*)((char*)d_ws + upk);
        unsigned long long* hglob = (unsigned long long*)((char*)d_ws + upk + wpk);
        zero_hglob<<<dim3(64), dim3(256), 0, stream>>>(hglob);
        pack_slices<<<dim3(8, 4), dim3(128), 0, stream>>>(U, Upack, 256);
        pack_slices<<<dim3(8, 2), dim3(128), 0, stream>>>(W, Wpack, 128);
        lstm_fuse<<<dim3(256), dim3(512), 0, stream>>>(
            X, Upack, Wpack, bias, h0, c0, hglob, out);
        return;
    }

    // --- R2 fallback: no workspace ---
    lstm_persist<<<dim3(BB), dim3(512), 0, stream>>>(X, W, U, bias, h0, c0, out);
}